// Round 7
// baseline (20.055 us; speedup 1.0000x reference)
//
#include <hip/hip_runtime.h>

// BoxCrossAttention: softmax over a length-1 key axis == 1.0, so
// out[b,c,w,h] = 9 * (vp[b] @ Wo + bo)[c],  vp = (mish(y@W1+b1)@W2+b2)[:,512:] @ Wv + bv.
// x / conv / unfold / q / k projections are dead code.
//
// R4: global spin-sync mega-kernel = 439us — dead end (XCD fence/poll storm).
// R5: M9=Wv@Wo folding = 29.7us — 33M MACs, 8x the live network. Dead end.
// R6: 3-node chain {hidden} -> {v_raw + vp outer-product partials} -> {o9+bcast}
//     = 19.9us. 3 nodes is structurally minimal (3 needs-all handoffs).
// R7: micro-opts: K1 256 blocks; K2 float4 staging; K3 early Wo load +
//     single-sync per-wave butterfly reduce.

__device__ __forceinline__ float mishf(float v) {
    float sp = (v > 20.0f) ? v : log1pf(expf(v));
    return v * tanhf(sp);
}

// K1: hidden[b][j] = mish(b1[j] + sum_t y[b][t]*W1[t][j]); grid 256 = 4b x 64 jslices(16)
__global__ __launch_bounds__(256) void k_hidden(const float* __restrict__ y,
                                                const float* __restrict__ W1,
                                                const float* __restrict__ b1,
                                                float* __restrict__ hidden) {
    int b  = blockIdx.x >> 6;
    int j0 = (blockIdx.x & 63) * 16;
    int t  = threadIdx.x;
    int col = j0 + (t & 15);
    int kc  = t >> 4;                        // 0..15, 16 rows each
    __shared__ float y_s[256];
    __shared__ float ps[256];
    y_s[t] = y[b * 256 + t];
    __syncthreads();
    const float* w  = W1 + (size_t)(kc * 16) * 1024 + col;
    const float* ys = y_s + kc * 16;
    float a0 = 0, a1 = 0, a2 = 0, a3 = 0;
    #pragma unroll
    for (int r = 0; r < 16; r += 4) {
        a0 = fmaf(ys[r + 0], w[(r + 0) * 1024], a0);
        a1 = fmaf(ys[r + 1], w[(r + 1) * 1024], a1);
        a2 = fmaf(ys[r + 2], w[(r + 2) * 1024], a2);
        a3 = fmaf(ys[r + 3], w[(r + 3) * 1024], a3);
    }
    ps[t] = (a0 + a1) + (a2 + a3);
    __syncthreads();
    if (t < 16) {
        float s = 0;
        #pragma unroll
        for (int k = 0; k < 16; ++k) s += ps[t + 16 * k];
        hidden[b * 1024 + j0 + t] = mishf(s + b1[j0 + t]);
    }
}

// K2: v_raw[b][c] for 16 cols, then this block's vp partial outer-product:
// vp_part[blockIdx][d] = sum_{k<16} v_raw[b][c0+k] * Wv[c0+k][d].  grid 128.
__global__ __launch_bounds__(256) void k_vraw_vppart(const float* __restrict__ hidden,
                                                     const float* __restrict__ W2,
                                                     const float* __restrict__ b2,
                                                     const float* __restrict__ Wv,
                                                     float* __restrict__ vp_part) {
    int b  = blockIdx.x >> 5;
    int c0 = (blockIdx.x & 31) * 16;
    int t  = threadIdx.x;
    int col = c0 + (t & 15);
    int kc  = t >> 4;
    __shared__ float4 h4_s[256];             // 1024 floats, float4-staged
    __shared__ float ps[256];
    __shared__ float vr16[16];
    h4_s[t] = ((const float4*)(hidden + b * 1024))[t];
    __syncthreads();
    const float* h_s = (const float*)h4_s;
    const float* w  = W2 + (size_t)(kc * 64) * 1024 + 512 + col;
    const float* hs = h_s + kc * 64;
    float a0 = 0, a1 = 0, a2 = 0, a3 = 0;
    for (int r = 0; r < 64; r += 4) {
        a0 = fmaf(hs[r + 0], w[(size_t)(r + 0) * 1024], a0);
        a1 = fmaf(hs[r + 1], w[(size_t)(r + 1) * 1024], a1);
        a2 = fmaf(hs[r + 2], w[(size_t)(r + 2) * 1024], a2);
        a3 = fmaf(hs[r + 3], w[(size_t)(r + 3) * 1024], a3);
    }
    ps[t] = (a0 + a1) + (a2 + a3);
    __syncthreads();
    if (t < 16) {
        float s = 0;
        #pragma unroll
        for (int k = 0; k < 16; ++k) s += ps[t + 16 * k];
        vr16[t] = s + b2[512 + c0 + t];
    }
    __syncthreads();
    // partial outer product: 16 MACs/thread, Wv rows c0..c0+15, coalesced in t
    const float* wv = Wv + (size_t)c0 * 256 + t;
    float acc0 = 0, acc1 = 0;
    #pragma unroll
    for (int k = 0; k < 16; k += 2) {
        acc0 = fmaf(vr16[k],     wv[(k + 0) * 256], acc0);
        acc1 = fmaf(vr16[k + 1], wv[(k + 1) * 256], acc1);
    }
    vp_part[(size_t)blockIdx.x * 256 + t] = acc0 + acc1;
}

// K3: block (b,c): vp[t] = sum_{p<32} vp_part[b*32+p][t] + bv[t];
// o9 = 9*(dot(vp, Wo[:,c]) + bo[c]); broadcast over 4096 slots. grid 1024.
// Single __syncthreads; every wave butterfly-reduces redundantly.
__global__ __launch_bounds__(256) void k_out3(const float* __restrict__ vp_part,
                                              const float* __restrict__ bv,
                                              const float* __restrict__ Wo,
                                              const float* __restrict__ bo,
                                              float4* __restrict__ out) {
    int b = blockIdx.x >> 8, c = blockIdx.x & 255, t = threadIdx.x;
    __shared__ float red[256];
    float wo = Wo[(size_t)t * 256 + c];      // independent: issue before part-sum
    const float* vpp = vp_part + (size_t)b * 32 * 256 + t;
    float s0 = 0, s1 = 0, s2 = 0, s3 = 0;
    #pragma unroll
    for (int p = 0; p < 32; p += 4) {
        s0 += vpp[(p + 0) * 256];
        s1 += vpp[(p + 1) * 256];
        s2 += vpp[(p + 2) * 256];
        s3 += vpp[(p + 3) * 256];
    }
    float vpv = ((s0 + s1) + (s2 + s3)) + bv[t];
    red[t] = vpv * wo;
    __syncthreads();
    int l = t & 63;
    float s = (red[l] + red[l + 64]) + (red[l + 128] + red[l + 192]);
    s += __shfl_xor(s, 32);
    s += __shfl_xor(s, 16);
    s += __shfl_xor(s, 8);
    s += __shfl_xor(s, 4);
    s += __shfl_xor(s, 2);
    s += __shfl_xor(s, 1);
    float v = 9.0f * (s + bo[c]);
    float4 vv = make_float4(v, v, v, v);
    float4* p = out + (size_t)blockIdx.x * 1024;
    p[t]       = vv;
    p[t + 256] = vv;
    p[t + 512] = vv;
    p[t + 768] = vv;
}

// ---------------- fallback (proven round-2 kernels, 28KB ws) ----------------
__global__ __launch_bounds__(256) void k_vraw(const float* __restrict__ hidden,
                                              const float* __restrict__ W2,
                                              const float* __restrict__ b2,
                                              float* __restrict__ v_raw) {
    int b  = blockIdx.x >> 5;
    int c0 = (blockIdx.x & 31) * 16;
    int t  = threadIdx.x;
    int col = c0 + (t & 15);
    int kc  = t >> 4;
    __shared__ float h_s[1024];
    __shared__ float ps[256];
    h_s[t]       = hidden[b * 1024 + t];
    h_s[t + 256] = hidden[b * 1024 + t + 256];
    h_s[t + 512] = hidden[b * 1024 + t + 512];
    h_s[t + 768] = hidden[b * 1024 + t + 768];
    __syncthreads();
    const float* w  = W2 + (size_t)(kc * 64) * 1024 + 512 + col;
    const float* hs = h_s + kc * 64;
    float a0 = 0, a1 = 0, a2 = 0, a3 = 0;
    for (int r = 0; r < 64; r += 4) {
        a0 = fmaf(hs[r + 0], w[(size_t)(r + 0) * 1024], a0);
        a1 = fmaf(hs[r + 1], w[(size_t)(r + 1) * 1024], a1);
        a2 = fmaf(hs[r + 2], w[(size_t)(r + 2) * 1024], a2);
        a3 = fmaf(hs[r + 3], w[(size_t)(r + 3) * 1024], a3);
    }
    ps[t] = (a0 + a1) + (a2 + a3);
    __syncthreads();
    if (t < 16) {
        float s = 0;
        #pragma unroll
        for (int k = 0; k < 16; ++k) s += ps[t + 16 * k];
        v_raw[b * 512 + c0 + t] = s + b2[512 + c0 + t];
    }
}

__global__ __launch_bounds__(256) void k_vp(const float* __restrict__ v_raw,
                                            const float* __restrict__ Wv,
                                            const float* __restrict__ bv,
                                            float* __restrict__ vp) {
    int b  = blockIdx.x >> 3;
    int d0 = (blockIdx.x & 7) * 32;
    int t  = threadIdx.x;
    int col = d0 + (t & 31), kc = t >> 5;
    __shared__ float v_s[512];
    __shared__ float ps[256];
    v_s[t]       = v_raw[b * 512 + t];
    v_s[t + 256] = v_raw[b * 512 + t + 256];
    __syncthreads();
    const float* w  = Wv + (size_t)(kc * 64) * 256 + col;
    const float* vs = v_s + kc * 64;
    float a0 = 0, a1 = 0, a2 = 0, a3 = 0;
    for (int r = 0; r < 64; r += 4) {
        a0 = fmaf(vs[r + 0], w[(r + 0) * 256], a0);
        a1 = fmaf(vs[r + 1], w[(r + 1) * 256], a1);
        a2 = fmaf(vs[r + 2], w[(r + 2) * 256], a2);
        a3 = fmaf(vs[r + 3], w[(r + 3) * 256], a3);
    }
    ps[t] = (a0 + a1) + (a2 + a3);
    __syncthreads();
    if (t < 32) {
        float s = 0;
        #pragma unroll
        for (int k = 0; k < 8; ++k) s += ps[t + 32 * k];
        vp[b * 256 + d0 + t] = s + bv[d0 + t];
    }
}

__global__ __launch_bounds__(256) void k_out(const float* __restrict__ vp,
                                             const float* __restrict__ Wo,
                                             const float* __restrict__ bo,
                                             float4* __restrict__ out) {
    int b = blockIdx.x >> 8, c = blockIdx.x & 255, t = threadIdx.x;
    __shared__ float red[256];
    red[t] = vp[b * 256 + t] * Wo[(size_t)t * 256 + c];
    __syncthreads();
    if (t < 64) {
        float s = (red[t] + red[t + 64]) + (red[t + 128] + red[t + 192]);
        s += __shfl_down(s, 32);
        s += __shfl_down(s, 16);
        s += __shfl_down(s, 8);
        s += __shfl_down(s, 4);
        s += __shfl_down(s, 2);
        s += __shfl_down(s, 1);
        if (t == 0) red[0] = 9.0f * (s + bo[c]);
    }
    __syncthreads();
    float v = red[0];
    float4 vv = make_float4(v, v, v, v);
    float4* p = out + (size_t)blockIdx.x * 1024;
    p[t]       = vv;
    p[t + 256] = vv;
    p[t + 512] = vv;
    p[t + 768] = vv;
}

extern "C" void kernel_launch(void* const* d_in, const int* in_sizes, int n_in,
                              void* d_out, int out_size, void* d_ws, size_t ws_size,
                              hipStream_t stream) {
    // 0:x 1:y 2:Wp 3:bp 4:W1 5:b1 6:W2 7:b2 8:Wq 9:bq 10:Wk 11:bk 12:Wv 13:bv 14:Wo 15:bo
    const float* y  = (const float*)d_in[1];
    const float* W1 = (const float*)d_in[4];
    const float* b1 = (const float*)d_in[5];
    const float* W2 = (const float*)d_in[6];
    const float* b2 = (const float*)d_in[7];
    const float* Wv = (const float*)d_in[12];
    const float* bv = (const float*)d_in[13];
    const float* Wo = (const float*)d_in[14];
    const float* bo = (const float*)d_in[15];

    float* ws      = (float*)d_ws;
    float* hidden  = ws;          // 4096 floats
    float* vp_part = ws + 4096;   // 128 blocks x 256 = 32768 floats
    const size_t need = (size_t)(4096 + 32768) * 4;   // 147KB

    if (ws_size >= need) {
        k_hidden     <<<256,  256, 0, stream>>>(y, W1, b1, hidden);
        k_vraw_vppart<<<128,  256, 0, stream>>>(hidden, W2, b2, Wv, vp_part);
        k_out3       <<<1024, 256, 0, stream>>>(vp_part, bv, Wo, bo, (float4*)d_out);
    } else {
        float* v_raw = ws + 4096;  // 2048
        float* vp    = ws + 6144;  // 1024
        k_hidden<<<256,  256, 0, stream>>>(y, W1, b1, hidden);
        k_vraw  <<<128,  256, 0, stream>>>(hidden, W2, b2, v_raw);
        k_vp    <<<32,   256, 0, stream>>>(v_raw, Wv, bv, vp);
        k_out   <<<1024, 256, 0, stream>>>(vp, Wo, bo, (float4*)d_out);
    }
}